// Round 8
// baseline (456.300 us; speedup 1.0000x reference)
//
#include <hip/hip_runtime.h>
#include <hip/hip_bf16.h>
#include <math.h>

#define B_ 2
#define L_ 2048
#define D_ 2048
#define H_ 16
#define HD_ 128
#define E_ (B_*L_*D_)   // 8388608
#define W_ (D_*D_)      // 4194304

typedef __bf16 bf16;
typedef __bf16 bf16x8 __attribute__((ext_vector_type(8)));
typedef __bf16 bf16x4 __attribute__((ext_vector_type(4)));
typedef float  f32x4  __attribute__((ext_vector_type(4)));

// async global->LDS, 16B per lane; lds ptr must be wave-uniform
#define GLL16(gp_, lp_) __builtin_amdgcn_global_load_lds( \
    (const __attribute__((address_space(1))) void*)(gp_), \
    (__attribute__((address_space(3))) void*)(lp_), 16, 0, 0)

#define BARRIER() do { asm volatile("" ::: "memory"); \
    __builtin_amdgcn_s_barrier(); \
    asm volatile("" ::: "memory"); } while (0)

#define WAITN(N) asm volatile("s_waitcnt vmcnt(" #N ")" ::: "memory")
#define LGKM0SB() do { asm volatile("s_waitcnt lgkmcnt(0)" ::: "memory"); \
    __builtin_amdgcn_sched_barrier(0); } while (0)

// ---------------- prep: all f32->bf16 converts + rope table, one launch ----------------
__global__ void prep(const float* __restrict__ xq, const float* __restrict__ xkv,
                     const float* __restrict__ wq, const float* __restrict__ wk,
                     const float* __restrict__ wv, const float* __restrict__ wo,
                     bf16* __restrict__ xqb, bf16* __restrict__ xkvb,
                     bf16* __restrict__ wqb, bf16* __restrict__ wkb,
                     bf16* __restrict__ wvb, bf16* __restrict__ wob,
                     float* __restrict__ ct, float* __restrict__ st) {
  int g = blockIdx.x;
  if (g < 16384) {
    const float* s = (g < 8192) ? xq : xkv;
    bf16* d = (g < 8192) ? xqb : xkvb;
    int i = ((g & 8191) * 256 + threadIdx.x) * 4;
    f32x4 v = *reinterpret_cast<const f32x4*>(s + i);
    bf16x4 o; o[0]=(bf16)v[0]; o[1]=(bf16)v[1]; o[2]=(bf16)v[2]; o[3]=(bf16)v[3];
    *reinterpret_cast<bf16x4*>(d + i) = o;
  } else if (g < 32768) {
    int gg = g - 16384;
    int which = gg >> 12;
    const float* s = (which==0)?wq:(which==1)?wk:(which==2)?wv:wo;
    bf16* d = (which==0)?wqb:(which==1)?wkb:(which==2)?wvb:wob;
    int i = ((gg & 4095) * 256 + threadIdx.x) * 4;
    f32x4 v = *reinterpret_cast<const f32x4*>(s + i);
    bf16x4 o; o[0]=(bf16)v[0]; o[1]=(bf16)v[1]; o[2]=(bf16)v[2]; o[3]=(bf16)v[3];
    *reinterpret_cast<bf16x4*>(d + i) = o;
  } else {
    int idx = (g - 32768) * 256 + threadIdx.x;   // < 131072 = 2048*64
    int t = idx >> 6, i = idx & 63;
    float inv = powf(10000.0f, -2.0f * (float)i / 128.0f);
    float f = (float)t * inv;
    ct[t * 64 + i] = cosf(f);
    st[t * 64 + i] = sinf(f);
  }
}

// ---------------- fused QKV GEMM, 256x256 tile, 8-phase schedule ----------------
// grid (24,16): blockIdx.x>>3 = which (0=Q,1=K,2=V), 512 threads = 8 waves (2M x 4N),
// per-wave 128x64 output, BK=64, LDS 128KB double-buffered, counted-deep vmcnt.
__global__ __launch_bounds__(512, 2) void gemm_qkv256(
    const bf16* __restrict__ xq, const bf16* __restrict__ xkv,
    const bf16* __restrict__ wq, const bf16* __restrict__ wk, const bf16* __restrict__ wv,
    const float* __restrict__ ct, const float* __restrict__ st,
    bf16* __restrict__ Qo, bf16* __restrict__ Ko, bf16* __restrict__ Vt) {
  __shared__ bf16 Ab[2][256 * 64];   // 2 x 32 KB
  __shared__ bf16 Bb[2][256 * 64];   // 2 x 32 KB
  const int tid = threadIdx.x;
  const int w = tid >> 6, lane = tid & 63;
  const int l15 = lane & 15, lg = lane >> 4;
  const int wm = w >> 2, wn = w & 3;          // 2M x 4N wave grid
  const int which = blockIdx.x >> 3;
  const int n0 = (blockIdx.x & 7) * 256;
  const int m0 = blockIdx.y * 256;
  const bf16* A  = (which == 0) ? xq : xkv;
  const bf16* Wt = (which == 0) ? wq : ((which == 1) ? wk : wv);

  // staging constants: 4 calls x 512 threads = 2048 chunks (256 rows x 8 chunks)
  int rS[4], cS[4];
#pragma unroll
  for (int s = 0; s < 4; ++s) {
    int ch = s * 512 + tid;
    rS[s] = ch >> 3;
    cS[s] = ((ch & 7) ^ ((ch >> 3) & 7)) << 3;   // swizzled source chunk (elems)
  }

  auto stage = [&](int t, int buf) {
#pragma unroll
    for (int s = 0; s < 4; ++s) {
      GLL16(A  + (size_t)(m0 + rS[s]) * D_ + t * 64 + cS[s], &Ab[buf][0] + s * 4096 + w * 512);
      GLL16(Wt + (size_t)(n0 + rS[s]) * D_ + t * 64 + cS[s], &Bb[buf][0] + s * 4096 + w * 512);
    }
  };
  // read 16B frag of (row, chunk x) with inverse swizzle
#define RD(bufp, row, x) (*reinterpret_cast<const bf16x8*>((bufp) + (row) * 64 + (((x) ^ (l15 & 7)) << 3)))

  f32x4 acc[8][4];
#pragma unroll
  for (int i = 0; i < 8; ++i)
#pragma unroll
    for (int n = 0; n < 4; ++n) acc[i][n] = (f32x4){0.f, 0.f, 0.f, 0.f};

  stage(0, 0);
  WAITN(0);
  BARRIER();

  for (int t = 0; t < 32; ++t) {
    const bf16* Al = &Ab[t & 1][0];
    const bf16* Bl = &Bb[t & 1][0];
    bf16x8 af[4], bfr[4];
    const bool hn = (t + 1 < 32);

    // ---- phase 0: stage next tile, B(ks0) + A(mq0,ks0), MFMA quad (0..3, ks0)
    if (hn) stage(t + 1, (t & 1) ^ 1);
#pragma unroll
    for (int n = 0; n < 4; ++n) bfr[n] = RD(Bl, wn * 64 + n * 16 + l15, lg);
#pragma unroll
    for (int i = 0; i < 4; ++i) af[i] = RD(Al, wm * 128 + i * 16 + l15, lg);
    BARRIER(); LGKM0SB();
    __builtin_amdgcn_s_setprio(1);
#pragma unroll
    for (int i = 0; i < 4; ++i)
#pragma unroll
      for (int n = 0; n < 4; ++n)
        acc[i][n] = __builtin_amdgcn_mfma_f32_16x16x32_bf16(af[i], bfr[n], acc[i][n], 0, 0, 0);
    __builtin_amdgcn_s_setprio(0);
    BARRIER();

    // ---- phase 1: A(mq1,ks0), MFMA quad (4..7, ks0)
#pragma unroll
    for (int i = 0; i < 4; ++i) af[i] = RD(Al, wm * 128 + (4 + i) * 16 + l15, lg);
    BARRIER(); LGKM0SB();
    __builtin_amdgcn_s_setprio(1);
#pragma unroll
    for (int i = 0; i < 4; ++i)
#pragma unroll
      for (int n = 0; n < 4; ++n)
        acc[4 + i][n] = __builtin_amdgcn_mfma_f32_16x16x32_bf16(af[i], bfr[n], acc[4 + i][n], 0, 0, 0);
    __builtin_amdgcn_s_setprio(0);
    BARRIER();

    // ---- phase 2: B(ks1) + A(mq0,ks1), MFMA quad (0..3, ks1)
#pragma unroll
    for (int n = 0; n < 4; ++n) bfr[n] = RD(Bl, wn * 64 + n * 16 + l15, 4 + lg);
#pragma unroll
    for (int i = 0; i < 4; ++i) af[i] = RD(Al, wm * 128 + i * 16 + l15, 4 + lg);
    BARRIER(); LGKM0SB();
    __builtin_amdgcn_s_setprio(1);
#pragma unroll
    for (int i = 0; i < 4; ++i)
#pragma unroll
      for (int n = 0; n < 4; ++n)
        acc[i][n] = __builtin_amdgcn_mfma_f32_16x16x32_bf16(af[i], bfr[n], acc[i][n], 0, 0, 0);
    __builtin_amdgcn_s_setprio(0);
    BARRIER();

    // ---- phase 3: A(mq1,ks1), MFMA quad (4..7, ks1); deep-drain next tile
#pragma unroll
    for (int i = 0; i < 4; ++i) af[i] = RD(Al, wm * 128 + (4 + i) * 16 + l15, 4 + lg);
    BARRIER(); LGKM0SB();
    __builtin_amdgcn_s_setprio(1);
#pragma unroll
    for (int i = 0; i < 4; ++i)
#pragma unroll
      for (int n = 0; n < 4; ++n)
        acc[4 + i][n] = __builtin_amdgcn_mfma_f32_16x16x32_bf16(af[i], bfr[n], acc[4 + i][n], 0, 0, 0);
    __builtin_amdgcn_s_setprio(0);
    if (hn) WAITN(0);     // drain tile t+1 (issued 3.5 phases ago)
    BARRIER();            // -> all waves see tile t+1 landed before next ds_reads
  }
#undef RD

  if (which == 2) {
    // V: write directly transposed into Vt[(b*16+h)*128+d][l]
    const int b = m0 >> 11;
#pragma unroll
    for (int mi = 0; mi < 8; ++mi) {
      int row = m0 + wm * 128 + mi * 16 + lg * 4;
      int l = row & 2047;
#pragma unroll
      for (int ni = 0; ni < 4; ++ni) {
        int c = n0 + wn * 64 + ni * 16 + l15;
        int hd = (b * 16 + (c >> 7)) * 128 + (c & 127);
        bf16x4 o;
        o[0] = (bf16)acc[mi][ni][0]; o[1] = (bf16)acc[mi][ni][1];
        o[2] = (bf16)acc[mi][ni][2]; o[3] = (bf16)acc[mi][ni][3];
        *reinterpret_cast<bf16x4*>(Vt + (size_t)hd * L_ + l) = o;
      }
    }
  } else {
    // Q/K: RoPE epilogue (pair partner in lane l15^1)
    bf16* Out = which ? Ko : Qo;
    const bool odd = (l15 & 1);
#pragma unroll
    for (int mi = 0; mi < 8; ++mi) {
      int row = m0 + wm * 128 + mi * 16 + lg * 4;
      int l = row & 2047;
#pragma unroll
      for (int ni = 0; ni < 4; ++ni) {
        int c = n0 + wn * 64 + ni * 16 + l15;
        int i = (c & 127) >> 1;
#pragma unroll
        for (int r = 0; r < 4; ++r) {
          float own = acc[mi][ni][r];
          float prt = __shfl_xor(own, 1, 64);
          float cc = ct[(size_t)(l + r) * 64 + i];
          float ss = st[(size_t)(l + r) * 64 + i];
          float res = odd ? (prt * ss + own * cc) : (own * cc - prt * ss);
          Out[(size_t)(row + r) * D_ + c] = (bf16)res;
        }
      }
    }
  }
}

// ---------------- GEMM: C[M,N] = A[M,K] @ Bw[N,K]^T (m97 structure, f32 out) ----------------
__global__ __launch_bounds__(256, 4) void gemm_bt(const bf16* __restrict__ A,
                                                  const bf16* __restrict__ Bw,
                                                  float* __restrict__ Cout,
                                                  int M, int N, int K) {
  __shared__ bf16 As[128 * 64];
  __shared__ bf16 Bs[128 * 64];
  const int tid = threadIdx.x;
  const int lane = tid & 63;
  const int w = tid >> 6;
  const int l15 = lane & 15, lg = lane >> 4;
  const int m0 = blockIdx.y * 128, n0 = blockIdx.x * 128;
  const int wm = (w >> 1) * 64, wn = (w & 1) * 64;

  int rowS[4], schS[4];
#pragma unroll
  for (int s = 0; s < 4; ++s) {
    int cl = s * 256 + tid;
    rowS[s] = cl >> 3;
    schS[s] = ((cl & 7) ^ ((cl >> 3) & 7)) << 3;
  }

  f32x4 acc[4][4];
#pragma unroll
  for (int m = 0; m < 4; ++m)
#pragma unroll
    for (int n = 0; n < 4; ++n) acc[m][n] = (f32x4){0.f, 0.f, 0.f, 0.f};

  for (int kt = 0; kt < K; kt += 64) {
    __syncthreads();
#pragma unroll
    for (int s = 0; s < 4; ++s) {
      GLL16(A  + (size_t)(m0 + rowS[s]) * K + kt + schS[s], As + s * 2048 + w * 512);
      GLL16(Bw + (size_t)(n0 + rowS[s]) * K + kt + schS[s], Bs + s * 2048 + w * 512);
    }
    __syncthreads();
#pragma unroll
    for (int kk = 0; kk < 64; kk += 32) {
      bf16x8 af[4], bfr[4];
#pragma unroll
      for (int m = 0; m < 4; ++m)
        af[m] = *reinterpret_cast<const bf16x8*>(
            As + (wm + m * 16 + l15) * 64 + ((((kk >> 3) + lg) ^ (l15 & 7)) << 3));
#pragma unroll
      for (int n = 0; n < 4; ++n)
        bfr[n] = *reinterpret_cast<const bf16x8*>(
            Bs + (wn + n * 16 + l15) * 64 + ((((kk >> 3) + lg) ^ (l15 & 7)) << 3));
#pragma unroll
      for (int m = 0; m < 4; ++m)
#pragma unroll
        for (int n = 0; n < 4; ++n)
          acc[m][n] = __builtin_amdgcn_mfma_f32_16x16x32_bf16(af[m], bfr[n], acc[m][n], 0, 0, 0);
    }
  }
#pragma unroll
  for (int m = 0; m < 4; ++m) {
    int orow = m0 + wm + m * 16 + lg * 4;
#pragma unroll
    for (int n = 0; n < 4; ++n) {
      int col = n0 + wn + n * 16 + l15;
#pragma unroll
      for (int r = 0; r < 4; ++r)
        Cout[(size_t)(orow + r) * N + col] = acc[m][n][r];
    }
  }
}

// ---------------- fused causal attention (round-6 version, reverted) ----------------
__global__ __launch_bounds__(256, 2) void attn_fused(const bf16* __restrict__ Qb,
                                                     const bf16* __restrict__ Kb,
                                                     const bf16* __restrict__ Vt,
                                                     float* __restrict__ attn,
                                                     bf16* __restrict__ Oh) {
  __shared__ bf16 Klds[2][64 * 128];   // 32 KB
  __shared__ bf16 Vlds[128 * 64];      // 16 KB
  __shared__ bf16 Plds[4][32][72];     // 18 KB

  const int tid = threadIdx.x;
  const int w = tid >> 6, lane = tid & 63;
  const int l15 = lane & 15, lg = lane >> 4;

  int g = blockIdx.x + 16 * blockIdx.y;
  int tq, bh;
  if (g < 256) { tq = g & 15;  bh = g >> 4; }
  else { int h2 = g - 256; tq = 15 - (h2 & 15); bh = 16 + (h2 >> 4); }
  const int b = bh >> 4, h = bh & 15;

  const int q0w = tq * 128 + w * 32;
  const int ntW = (q0w >> 6) + 1;
  const int ntB = 2 * tq + 2;
  const float sc2 = 0.08838834764831845f * 1.44269504088896f;

  const bf16* kb = Kb + ((size_t)b * L_) * D_ + h * HD_;
  const bf16* vb = Vt + (size_t)bh * HD_ * L_;
  float* arow = attn + ((size_t)bh * L_ + q0w) * L_;

  bf16x8 qf[2][4];
#pragma unroll
  for (int qc = 0; qc < 2; ++qc) {
    const bf16* qrow = Qb + ((size_t)b * L_ + q0w + qc * 16 + l15) * D_ + h * HD_;
#pragma unroll
    for (int c = 0; c < 4; ++c)
      qf[qc][c] = *reinterpret_cast<const bf16x8*>(qrow + c * 32 + lg * 8);
  }

  int rK[4], sK[4], rV[4], sV[4];
#pragma unroll
  for (int s = 0; s < 4; ++s) {
    int ck = s * 256 + tid;
    rK[s] = ck >> 4; sK[s] = ((ck & 15) ^ (rK[s] & 7)) << 3;
    rV[s] = ck >> 3; sV[s] = ((ck & 7) ^ (rV[s] & 7)) << 3;
  }

  auto stageK = [&](int gp, int buf) {
#pragma unroll
    for (int s = 0; s < 4; ++s)
      GLL16(kb + (size_t)(gp * 64 + rK[s]) * D_ + sK[s],
            &Klds[0][0] + buf * 8192 + s * 2048 + w * 512);
  };
  auto stageV = [&](int gp) {
#pragma unroll
    for (int s = 0; s < 4; ++s)
      GLL16(vb + (size_t)rV[s] * L_ + gp * 64 + sV[s],
            Vlds + s * 2048 + w * 512);
  };
  auto qkt = [&](const bf16* kl, f32x4 acc[2][4]) {
#pragma unroll
    for (int c = 0; c < 4; ++c)
#pragma unroll
      for (int t = 0; t < 4; ++t) {
        bf16x8 kf = *reinterpret_cast<const bf16x8*>(
            kl + (t * 16 + l15) * 128 + ((((c << 2) + lg) ^ (l15 & 7)) << 3));
#pragma unroll
        for (int qc = 0; qc < 2; ++qc)
          acc[qc][t] = __builtin_amdgcn_mfma_f32_16x16x32_bf16(qf[qc][c], kf, acc[qc][t], 0, 0, 0);
      }
  };
  auto zstore32 = [&](int gp) {
#pragma unroll
    for (int qc = 0; qc < 2; ++qc)
#pragma unroll
      for (int t = 0; t < 4; ++t)
#pragma unroll
        for (int r = 0; r < 4; ++r)
          arow[(size_t)(qc * 16 + lg * 4 + r) * L_ + gp * 64 + t * 16 + l15] = 0.f;
  };

  // ---- pass 1: row sums ----
  float sum[2][4] = {{0.f,0.f,0.f,0.f},{0.f,0.f,0.f,0.f}};
  stageK(0, 0);
  for (int gp = 0; gp < ntB; ++gp) {
    BARRIER();
    const bool hn = (gp + 1 < ntB);
    if (hn) { stageK(gp + 1, (gp + 1) & 1); WAITN(4); }
    else    { WAITN(0); }
    BARRIER();
    if (gp < ntW) {
      f32x4 acc[2][4];
#pragma unroll
      for (int qc = 0; qc < 2; ++qc)
#pragma unroll
        for (int t = 0; t < 4; ++t) acc[qc][t] = (f32x4){0.f,0.f,0.f,0.f};
      qkt(&Klds[gp & 1][0], acc);
      if (gp < ntW - 1) {
#pragma unroll
        for (int qc = 0; qc < 2; ++qc)
#pragma unroll
          for (int t = 0; t < 4; ++t)
#pragma unroll
            for (int r = 0; r < 4; ++r)
              sum[qc][r] += exp2f(acc[qc][t][r] * sc2);
      } else {
#pragma unroll
        for (int qc = 0; qc < 2; ++qc)
#pragma unroll
          for (int t = 0; t < 4; ++t)
#pragma unroll
            for (int r = 0; r < 4; ++r) {
              int kc = gp * 64 + t * 16 + l15;
              int qr = q0w + qc * 16 + lg * 4 + r;
              sum[qc][r] += (kc <= qr) ? exp2f(acc[qc][t][r] * sc2) : 0.f;
            }
      }
    } else {
      zstore32(gp);
    }
  }
  float rinv[2][4];
#pragma unroll
  for (int qc = 0; qc < 2; ++qc)
#pragma unroll
    for (int r = 0; r < 4; ++r) {
      float s = sum[qc][r];
#pragma unroll
      for (int sh = 1; sh < 16; sh <<= 1)
        s += __shfl_xor(s, sh, 64);
      rinv[qc][r] = 1.0f / s;
    }

  // ---- pass 2 ----
  f32x4 oacc[2][8];
#pragma unroll
  for (int qc = 0; qc < 2; ++qc)
#pragma unroll
    for (int i = 0; i < 8; ++i) oacc[qc][i] = (f32x4){0.f, 0.f, 0.f, 0.f};

  BARRIER();
  stageK(0, 0);
  for (int gp = 0; gp < ntB; ++gp) {
    BARRIER();
    stageV(gp);
    const bool hn = (gp + 1 < ntB);
    if (hn) stageK(gp + 1, (gp + 1) & 1);
    if (gp == 0) { WAITN(8); }
    else if (hn) { WAITN(40); }
    else         { WAITN(36); }
    BARRIER();
    const bool act = gp < ntW;
    float pv[2][4][4];
    if (act) {
      f32x4 acc[2][4];
#pragma unroll
      for (int qc = 0; qc < 2; ++qc)
#pragma unroll
        for (int t = 0; t < 4; ++t) acc[qc][t] = (f32x4){0.f,0.f,0.f,0.f};
      qkt(&Klds[gp & 1][0], acc);
      if (gp < ntW - 1) {
#pragma unroll
        for (int qc = 0; qc < 2; ++qc)
#pragma unroll
          for (int t = 0; t < 4; ++t)
#pragma unroll
            for (int r = 0; r < 4; ++r)
              pv[qc][t][r] = exp2f(acc[qc][t][r] * sc2) * rinv[qc][r];
      } else {
#pragma unroll
        for (int qc = 0; qc < 2; ++qc)
#pragma unroll
          for (int t = 0; t < 4; ++t)
#pragma unroll
            for (int r = 0; r < 4; ++r) {
              int kc = gp * 64 + t * 16 + l15;
              int qr = q0w + qc * 16 + lg * 4 + r;
              pv[qc][t][r] = (kc <= qr) ? exp2f(acc[qc][t][r] * sc2) * rinv[qc][r] : 0.f;
            }
      }
#pragma unroll
      for (int qc = 0; qc < 2; ++qc)
#pragma unroll
        for (int t = 0; t < 4; ++t)
#pragma unroll
          for (int r = 0; r < 4; ++r)
            Plds[w][qc * 16 + lg * 4 + r][t * 16 + l15] = (bf16)pv[qc][t][r];
    }
    if (hn) WAITN(4); else WAITN(0);
    if (act) {
#pragma unroll
      for (int qc = 0; qc < 2; ++qc)
#pragma unroll
        for (int t = 0; t < 4; ++t)
#pragma unroll
          for (int r = 0; r < 4; ++r)
            arow[(size_t)(qc * 16 + lg * 4 + r) * L_ + gp * 64 + t * 16 + l15] = pv[qc][t][r];
    } else {
      zstore32(gp);
    }
    BARRIER();
    if (act) {
      asm volatile("s_waitcnt lgkmcnt(0)" ::: "memory");
      __builtin_amdgcn_sched_barrier(0);
      bf16x8 pa[2][2];
#pragma unroll
      for (int qc = 0; qc < 2; ++qc)
#pragma unroll
        for (int ck = 0; ck < 2; ++ck)
          pa[qc][ck] = *reinterpret_cast<const bf16x8*>(&Plds[w][qc * 16 + l15][ck * 32 + lg * 8]);
#pragma unroll
      for (int ck = 0; ck < 2; ++ck)
#pragma unroll
        for (int t8 = 0; t8 < 8; ++t8) {
          bf16x8 vf = *reinterpret_cast<const bf16x8*>(
              Vlds + (t8 * 16 + l15) * 64 + ((((ck << 2) + lg) ^ (l15 & 7)) << 3));
#pragma unroll
          for (int qc = 0; qc < 2; ++qc)
            oacc[qc][t8] = __builtin_amdgcn_mfma_f32_16x16x32_bf16(pa[qc][ck], vf, oacc[qc][t8], 0, 0, 0);
        }
      asm volatile("s_waitcnt lgkmcnt(0)" ::: "memory");
    }
  }

  for (int gp2 = ntB; gp2 < 32; ++gp2) {
#pragma unroll
    for (int i = 0; i < 8; ++i)
      *reinterpret_cast<f32x4*>(arow + (size_t)(i * 4 + lg) * L_ + gp2 * 64 + l15 * 4)
          = (f32x4){0.f, 0.f, 0.f, 0.f};
  }

#pragma unroll
  for (int qc = 0; qc < 2; ++qc) {
    bf16* orow = Oh + ((size_t)b * L_ + q0w + qc * 16) * D_ + h * HD_;
#pragma unroll
    for (int t8 = 0; t8 < 8; ++t8)
#pragma unroll
      for (int r = 0; r < 4; ++r)
        orow[(size_t)(lg * 4 + r) * D_ + t8 * 16 + l15] = (bf16)oacc[qc][t8][r];
  }
}

// ---------------- host ----------------
extern "C" void kernel_launch(void* const* d_in, const int* in_sizes, int n_in,
                              void* d_out, int out_size, void* d_ws, size_t ws_size,
                              hipStream_t stream) {
  const float* x_q  = (const float*)d_in[0];
  const float* x_kv = (const float*)d_in[1];
  const float* w_q = (const float*)d_in[3];
  const float* w_k = (const float*)d_in[4];
  const float* w_v = (const float*)d_in[5];
  const float* w_o = (const float*)d_in[6];

  char* p = (char*)d_ws;
  auto alloc = [&](size_t bytes) { char* r = p; p += (bytes + 255) & ~(size_t)255; return r; };
  bf16* xq_b  = (bf16*)alloc((size_t)E_ * 2);
  bf16* xkv_b = (bf16*)alloc((size_t)E_ * 2);
  bf16* wq_b  = (bf16*)alloc((size_t)W_ * 2);
  bf16* wk_b  = (bf16*)alloc((size_t)W_ * 2);
  bf16* wv_b  = (bf16*)alloc((size_t)W_ * 2);
  bf16* wo_b  = (bf16*)alloc((size_t)W_ * 2);
  bf16* Qraw  = (bf16*)alloc((size_t)E_ * 2);
  bf16* Kraw  = (bf16*)alloc((size_t)E_ * 2);
  bf16* Vt    = (bf16*)alloc((size_t)E_ * 2);
  bf16* Oh    = (bf16*)alloc((size_t)E_ * 2);
  float* ct   = (float*)alloc((size_t)L_ * 64 * 4);
  float* st2  = (float*)alloc((size_t)L_ * 64 * 4);

  float* out0     = (float*)d_out;
  float* attn_out = out0 + E_;

  prep<<<33280, 256, 0, stream>>>(x_q, x_kv, w_q, w_k, w_v, w_o,
                                  xq_b, xkv_b, wq_b, wk_b, wv_b, wo_b, ct, st2);
  gemm_qkv256<<<dim3(24, 16), 512, 0, stream>>>(xq_b, xkv_b, wq_b, wk_b, wv_b,
                                                ct, st2, Qraw, Kraw, Vt);
  attn_fused<<<dim3(16, 32), 256, 0, stream>>>(Qraw, Kraw, Vt, attn_out, Oh);
  gemm_bt<<<dim3(16, 32), 256, 0, stream>>>(Oh, wo_b, out0, B_*L_, D_, D_);
}

// Round 9
// 409.334 us; speedup vs baseline: 1.1147x; 1.1147x over previous
//
#include <hip/hip_runtime.h>
#include <hip/hip_bf16.h>
#include <math.h>

#define B_ 2
#define L_ 2048
#define D_ 2048
#define H_ 16
#define HD_ 128
#define E_ (B_*L_*D_)   // 8388608
#define W_ (D_*D_)      // 4194304

typedef __bf16 bf16;
typedef __bf16 bf16x8 __attribute__((ext_vector_type(8)));
typedef __bf16 bf16x4 __attribute__((ext_vector_type(4)));
typedef float  f32x4  __attribute__((ext_vector_type(4)));

// async global->LDS, 16B per lane; lds ptr must be wave-uniform
#define GLL16(gp_, lp_) __builtin_amdgcn_global_load_lds( \
    (const __attribute__((address_space(1))) void*)(gp_), \
    (__attribute__((address_space(3))) void*)(lp_), 16, 0, 0)

#define BARRIER() do { asm volatile("" ::: "memory"); \
    __builtin_amdgcn_s_barrier(); \
    asm volatile("" ::: "memory"); } while (0)

#define WAITN(N) asm volatile("s_waitcnt vmcnt(" #N ")" ::: "memory")
#define LGKM0SB() do { asm volatile("s_waitcnt lgkmcnt(0)" ::: "memory"); \
    __builtin_amdgcn_sched_barrier(0); } while (0)

// ---------------- prep: all f32->bf16 converts + rope table, one launch ----------------
__global__ void prep(const float* __restrict__ xq, const float* __restrict__ xkv,
                     const float* __restrict__ wq, const float* __restrict__ wk,
                     const float* __restrict__ wv, const float* __restrict__ wo,
                     bf16* __restrict__ xqb, bf16* __restrict__ xkvb,
                     bf16* __restrict__ wqb, bf16* __restrict__ wkb,
                     bf16* __restrict__ wvb, bf16* __restrict__ wob,
                     float* __restrict__ ct, float* __restrict__ st) {
  int g = blockIdx.x;
  if (g < 16384) {
    const float* s = (g < 8192) ? xq : xkv;
    bf16* d = (g < 8192) ? xqb : xkvb;
    int i = ((g & 8191) * 256 + threadIdx.x) * 4;
    f32x4 v = *reinterpret_cast<const f32x4*>(s + i);
    bf16x4 o; o[0]=(bf16)v[0]; o[1]=(bf16)v[1]; o[2]=(bf16)v[2]; o[3]=(bf16)v[3];
    *reinterpret_cast<bf16x4*>(d + i) = o;
  } else if (g < 32768) {
    int gg = g - 16384;
    int which = gg >> 12;
    const float* s = (which==0)?wq:(which==1)?wk:(which==2)?wv:wo;
    bf16* d = (which==0)?wqb:(which==1)?wkb:(which==2)?wvb:wob;
    int i = ((gg & 4095) * 256 + threadIdx.x) * 4;
    f32x4 v = *reinterpret_cast<const f32x4*>(s + i);
    bf16x4 o; o[0]=(bf16)v[0]; o[1]=(bf16)v[1]; o[2]=(bf16)v[2]; o[3]=(bf16)v[3];
    *reinterpret_cast<bf16x4*>(d + i) = o;
  } else {
    int idx = (g - 32768) * 256 + threadIdx.x;   // < 131072 = 2048*64
    int t = idx >> 6, i = idx & 63;
    float inv = powf(10000.0f, -2.0f * (float)i / 128.0f);
    float f = (float)t * inv;
    ct[t * 64 + i] = cosf(f);
    st[t * 64 + i] = sinf(f);
  }
}

// ---------------- fused QKV GEMM: BM=128 BN=256, 2-phase/K-tile, 3-buffer counted vmcnt ----
// grid (24, 32): which = bx>>3 (0=Q,1=K,2=V), n0 = (bx&7)*256, m0 = by*128.
// 512 threads = 8 waves (2M x 4N), per-wave 64x64 output. 768 blocks = 3.0 rounds exactly.
__global__ __launch_bounds__(512, 2) void gemm_qkv8p(
    const bf16* __restrict__ xq, const bf16* __restrict__ xkv,
    const bf16* __restrict__ wq, const bf16* __restrict__ wk, const bf16* __restrict__ wv,
    const float* __restrict__ ct, const float* __restrict__ st,
    bf16* __restrict__ Qo, bf16* __restrict__ Ko, bf16* __restrict__ Vt) {
  __shared__ bf16 Ab[3][128 * 64];   // 3 x 16 KB
  __shared__ bf16 Bb[3][256 * 64];   // 3 x 32 KB   (total 144 KB, 1 block/CU)
  const int tid = threadIdx.x;
  const int w = tid >> 6, lane = tid & 63;
  const int l15 = lane & 15, lg = lane >> 4;
  const int wm = w >> 2, wn = w & 3;               // 2M x 4N wave grid
  const int which = blockIdx.x >> 3;
  const int n0 = (blockIdx.x & 7) * 256;
  const int m0 = blockIdx.y * 128;
  const bf16* A  = (which == 0) ? xq : xkv;
  const bf16* Wt = (which == 0) ? wq : ((which == 1) ? wk : wv);

  // staging constants (chunk-XOR swizzled source)
  int rA[2], cA[2], rB[4], cB[4];
#pragma unroll
  for (int s = 0; s < 2; ++s) {
    int ch = s * 512 + tid; rA[s] = ch >> 3; cA[s] = ((ch & 7) ^ (rA[s] & 7)) << 3;
  }
#pragma unroll
  for (int s = 0; s < 4; ++s) {
    int ch = s * 512 + tid; rB[s] = ch >> 3; cB[s] = ((ch & 7) ^ (rB[s] & 7)) << 3;
  }
  auto stageA = [&](int t, int buf, int s) {
    GLL16(A + (size_t)(m0 + rA[s]) * D_ + t * 64 + cA[s], &Ab[buf][0] + s * 4096 + w * 512);
  };
  auto stageB = [&](int t, int buf, int s) {
    GLL16(Wt + (size_t)(n0 + rB[s]) * D_ + t * 64 + cB[s], &Bb[buf][0] + s * 4096 + w * 512);
  };
#define RDS(bufp, R, x) (*reinterpret_cast<const bf16x8*>((bufp) + (R) * 64 + (((x) ^ ((R) & 7)) << 3)))

  f32x4 acc[4][4];                   // [fr][fc]
#pragma unroll
  for (int i = 0; i < 4; ++i)
#pragma unroll
    for (int j = 0; j < 4; ++j) acc[i][j] = (f32x4){0.f, 0.f, 0.f, 0.f};

  // prologue: stage tiles 0 and 1; wait for tile 0 (6 of 12 outstanding remain)
#pragma unroll
  for (int s = 0; s < 2; ++s) stageA(0, 0, s);
#pragma unroll
  for (int s = 0; s < 4; ++s) stageB(0, 0, s);
#pragma unroll
  for (int s = 0; s < 2; ++s) stageA(1, 1, s);
#pragma unroll
  for (int s = 0; s < 4; ++s) stageB(1, 1, s);
  WAITN(6);
  BARRIER();

  bf16x8 afr[4][2];                  // A frags [fr][ks], live across both phases
  for (int t = 0; t < 32; ++t) {
    const bf16* Al = &Ab[t % 3][0];
    const bf16* Bl = &Bb[t % 3][0];
    const int nb = (t + 2) % 3;
    const bool stg = (t + 2 < 32);
    bf16x8 bfr[2][2];

    // ---- phase A: fc 0,1 ----
#pragma unroll
    for (int fr = 0; fr < 4; ++fr)
#pragma unroll
      for (int ks = 0; ks < 2; ++ks)
        afr[fr][ks] = RDS(Al, wm * 64 + fr * 16 + l15, ks * 4 + lg);
#pragma unroll
    for (int fc = 0; fc < 2; ++fc)
#pragma unroll
      for (int ks = 0; ks < 2; ++ks)
        bfr[fc][ks] = RDS(Bl, wn * 64 + fc * 16 + l15, ks * 4 + lg);
    if (stg) { stageA(t + 2, nb, 0); stageA(t + 2, nb, 1); stageB(t + 2, nb, 0); }
    BARRIER(); LGKM0SB();
    __builtin_amdgcn_s_setprio(1);
#pragma unroll
    for (int fr = 0; fr < 4; ++fr)
#pragma unroll
      for (int fc = 0; fc < 2; ++fc)
#pragma unroll
        for (int ks = 0; ks < 2; ++ks)
          acc[fr][fc] = __builtin_amdgcn_mfma_f32_16x16x32_bf16(afr[fr][ks], bfr[fc][ks], acc[fr][fc], 0, 0, 0);
    __builtin_amdgcn_s_setprio(0);
    BARRIER();

    // ---- phase B: fc 2,3 (reuse A frags) ----
#pragma unroll
    for (int fc = 0; fc < 2; ++fc)
#pragma unroll
      for (int ks = 0; ks < 2; ++ks)
        bfr[fc][ks] = RDS(Bl, wn * 64 + (2 + fc) * 16 + l15, ks * 4 + lg);
    if (stg) { stageB(t + 2, nb, 1); stageB(t + 2, nb, 2); stageB(t + 2, nb, 3); }
    BARRIER(); LGKM0SB();
    __builtin_amdgcn_s_setprio(1);
#pragma unroll
    for (int fr = 0; fr < 4; ++fr)
#pragma unroll
      for (int fc = 0; fc < 2; ++fc)
#pragma unroll
        for (int ks = 0; ks < 2; ++ks)
          acc[fr][2 + fc] = __builtin_amdgcn_mfma_f32_16x16x32_bf16(afr[fr][ks], bfr[fc][ks], acc[fr][2 + fc], 0, 0, 0);
    __builtin_amdgcn_s_setprio(0);
    if (t < 30) { if (stg) WAITN(6); else WAITN(0); }   // counted: tile t+1 landed, t+2 in flight
    BARRIER();
  }
#undef RDS

  if (which == 2) {
    // V: write directly transposed into Vt[(b*16+h)*128+d][l]
    const int b = m0 >> 11;
#pragma unroll
    for (int fr = 0; fr < 4; ++fr) {
      int l0 = (m0 & 2047) + wm * 64 + fr * 16 + lg * 4;
#pragma unroll
      for (int fc = 0; fc < 4; ++fc) {
        int c = n0 + wn * 64 + fc * 16 + l15;
        int hd = (b * 16 + (c >> 7)) * 128 + (c & 127);
        bf16x4 o;
        o[0] = (bf16)acc[fr][fc][0]; o[1] = (bf16)acc[fr][fc][1];
        o[2] = (bf16)acc[fr][fc][2]; o[3] = (bf16)acc[fr][fc][3];
        *reinterpret_cast<bf16x4*>(Vt + (size_t)hd * L_ + l0) = o;
      }
    }
  } else {
    // Q/K: RoPE epilogue (pair partner lives in lane l15^1)
    bf16* Out = which ? Ko : Qo;
    const bool odd = (l15 & 1);
#pragma unroll
    for (int fr = 0; fr < 4; ++fr) {
      int row = m0 + wm * 64 + fr * 16 + lg * 4;
      int l = row & 2047;
#pragma unroll
      for (int fc = 0; fc < 4; ++fc) {
        int c = n0 + wn * 64 + fc * 16 + l15;
        int i = (c & 127) >> 1;
#pragma unroll
        for (int r = 0; r < 4; ++r) {
          float own = acc[fr][fc][r];
          float prt = __shfl_xor(own, 1, 64);
          float cc = ct[(size_t)(l + r) * 64 + i];
          float ss = st[(size_t)(l + r) * 64 + i];
          float res = odd ? (prt * ss + own * cc) : (own * cc - prt * ss);
          Out[(size_t)(row + r) * D_ + c] = (bf16)res;
        }
      }
    }
  }
}

// ---------------- GEMM: C[M,N] = A[M,K] @ Bw[N,K]^T (m97 structure, f32 out) ----------------
__global__ __launch_bounds__(256, 4) void gemm_bt(const bf16* __restrict__ A,
                                                  const bf16* __restrict__ Bw,
                                                  float* __restrict__ Cout,
                                                  int M, int N, int K) {
  __shared__ bf16 As[128 * 64];
  __shared__ bf16 Bs[128 * 64];
  const int tid = threadIdx.x;
  const int lane = tid & 63;
  const int w = tid >> 6;
  const int l15 = lane & 15, lg = lane >> 4;
  const int m0 = blockIdx.y * 128, n0 = blockIdx.x * 128;
  const int wm = (w >> 1) * 64, wn = (w & 1) * 64;

  int rowS[4], schS[4];
#pragma unroll
  for (int s = 0; s < 4; ++s) {
    int cl = s * 256 + tid;
    rowS[s] = cl >> 3;
    schS[s] = ((cl & 7) ^ ((cl >> 3) & 7)) << 3;
  }

  f32x4 acc[4][4];
#pragma unroll
  for (int m = 0; m < 4; ++m)
#pragma unroll
    for (int n = 0; n < 4; ++n) acc[m][n] = (f32x4){0.f, 0.f, 0.f, 0.f};

  for (int kt = 0; kt < K; kt += 64) {
    __syncthreads();
#pragma unroll
    for (int s = 0; s < 4; ++s) {
      GLL16(A  + (size_t)(m0 + rowS[s]) * K + kt + schS[s], As + s * 2048 + w * 512);
      GLL16(Bw + (size_t)(n0 + rowS[s]) * K + kt + schS[s], Bs + s * 2048 + w * 512);
    }
    __syncthreads();
#pragma unroll
    for (int kk = 0; kk < 64; kk += 32) {
      bf16x8 af[4], bfr[4];
#pragma unroll
      for (int m = 0; m < 4; ++m)
        af[m] = *reinterpret_cast<const bf16x8*>(
            As + (wm + m * 16 + l15) * 64 + ((((kk >> 3) + lg) ^ (l15 & 7)) << 3));
#pragma unroll
      for (int n = 0; n < 4; ++n)
        bfr[n] = *reinterpret_cast<const bf16x8*>(
            Bs + (wn + n * 16 + l15) * 64 + ((((kk >> 3) + lg) ^ (l15 & 7)) << 3));
#pragma unroll
      for (int m = 0; m < 4; ++m)
#pragma unroll
        for (int n = 0; n < 4; ++n)
          acc[m][n] = __builtin_amdgcn_mfma_f32_16x16x32_bf16(af[m], bfr[n], acc[m][n], 0, 0, 0);
    }
  }
#pragma unroll
  for (int m = 0; m < 4; ++m) {
    int orow = m0 + wm + m * 16 + lg * 4;
#pragma unroll
    for (int n = 0; n < 4; ++n) {
      int col = n0 + wn + n * 16 + l15;
#pragma unroll
      for (int r = 0; r < 4; ++r)
        Cout[(size_t)(orow + r) * N + col] = acc[m][n][r];
    }
  }
}

// ---------------- fused causal attention (round-6 version) ----------------
__global__ __launch_bounds__(256, 2) void attn_fused(const bf16* __restrict__ Qb,
                                                     const bf16* __restrict__ Kb,
                                                     const bf16* __restrict__ Vt,
                                                     float* __restrict__ attn,
                                                     bf16* __restrict__ Oh) {
  __shared__ bf16 Klds[2][64 * 128];   // 32 KB
  __shared__ bf16 Vlds[128 * 64];      // 16 KB
  __shared__ bf16 Plds[4][32][72];     // 18 KB

  const int tid = threadIdx.x;
  const int w = tid >> 6, lane = tid & 63;
  const int l15 = lane & 15, lg = lane >> 4;

  int g = blockIdx.x + 16 * blockIdx.y;
  int tq, bh;
  if (g < 256) { tq = g & 15;  bh = g >> 4; }
  else { int h2 = g - 256; tq = 15 - (h2 & 15); bh = 16 + (h2 >> 4); }
  const int b = bh >> 4, h = bh & 15;

  const int q0w = tq * 128 + w * 32;
  const int ntW = (q0w >> 6) + 1;
  const int ntB = 2 * tq + 2;
  const float sc2 = 0.08838834764831845f * 1.44269504088896f;

  const bf16* kb = Kb + ((size_t)b * L_) * D_ + h * HD_;
  const bf16* vb = Vt + (size_t)bh * HD_ * L_;
  float* arow = attn + ((size_t)bh * L_ + q0w) * L_;

  bf16x8 qf[2][4];
#pragma unroll
  for (int qc = 0; qc < 2; ++qc) {
    const bf16* qrow = Qb + ((size_t)b * L_ + q0w + qc * 16 + l15) * D_ + h * HD_;
#pragma unroll
    for (int c = 0; c < 4; ++c)
      qf[qc][c] = *reinterpret_cast<const bf16x8*>(qrow + c * 32 + lg * 8);
  }

  int rK[4], sK[4], rV[4], sV[4];
#pragma unroll
  for (int s = 0; s < 4; ++s) {
    int ck = s * 256 + tid;
    rK[s] = ck >> 4; sK[s] = ((ck & 15) ^ (rK[s] & 7)) << 3;
    rV[s] = ck >> 3; sV[s] = ((ck & 7) ^ (rV[s] & 7)) << 3;
  }

  auto stageK = [&](int gp, int buf) {
#pragma unroll
    for (int s = 0; s < 4; ++s)
      GLL16(kb + (size_t)(gp * 64 + rK[s]) * D_ + sK[s],
            &Klds[0][0] + buf * 8192 + s * 2048 + w * 512);
  };
  auto stageV = [&](int gp) {
#pragma unroll
    for (int s = 0; s < 4; ++s)
      GLL16(vb + (size_t)rV[s] * L_ + gp * 64 + sV[s],
            Vlds + s * 2048 + w * 512);
  };
  auto qkt = [&](const bf16* kl, f32x4 acc[2][4]) {
#pragma unroll
    for (int c = 0; c < 4; ++c)
#pragma unroll
      for (int t = 0; t < 4; ++t) {
        bf16x8 kf = *reinterpret_cast<const bf16x8*>(
            kl + (t * 16 + l15) * 128 + ((((c << 2) + lg) ^ (l15 & 7)) << 3));
#pragma unroll
        for (int qc = 0; qc < 2; ++qc)
          acc[qc][t] = __builtin_amdgcn_mfma_f32_16x16x32_bf16(qf[qc][c], kf, acc[qc][t], 0, 0, 0);
      }
  };
  auto zstore32 = [&](int gp) {
#pragma unroll
    for (int qc = 0; qc < 2; ++qc)
#pragma unroll
      for (int t = 0; t < 4; ++t)
#pragma unroll
        for (int r = 0; r < 4; ++r)
          arow[(size_t)(qc * 16 + lg * 4 + r) * L_ + gp * 64 + t * 16 + l15] = 0.f;
  };

  // ---- pass 1: row sums ----
  float sum[2][4] = {{0.f,0.f,0.f,0.f},{0.f,0.f,0.f,0.f}};
  stageK(0, 0);
  for (int gp = 0; gp < ntB; ++gp) {
    BARRIER();
    const bool hn = (gp + 1 < ntB);
    if (hn) { stageK(gp + 1, (gp + 1) & 1); WAITN(4); }
    else    { WAITN(0); }
    BARRIER();
    if (gp < ntW) {
      f32x4 acc[2][4];
#pragma unroll
      for (int qc = 0; qc < 2; ++qc)
#pragma unroll
        for (int t = 0; t < 4; ++t) acc[qc][t] = (f32x4){0.f,0.f,0.f,0.f};
      qkt(&Klds[gp & 1][0], acc);
      if (gp < ntW - 1) {
#pragma unroll
        for (int qc = 0; qc < 2; ++qc)
#pragma unroll
          for (int t = 0; t < 4; ++t)
#pragma unroll
            for (int r = 0; r < 4; ++r)
              sum[qc][r] += exp2f(acc[qc][t][r] * sc2);
      } else {
#pragma unroll
        for (int qc = 0; qc < 2; ++qc)
#pragma unroll
          for (int t = 0; t < 4; ++t)
#pragma unroll
            for (int r = 0; r < 4; ++r) {
              int kc = gp * 64 + t * 16 + l15;
              int qr = q0w + qc * 16 + lg * 4 + r;
              sum[qc][r] += (kc <= qr) ? exp2f(acc[qc][t][r] * sc2) : 0.f;
            }
      }
    } else {
      zstore32(gp);
    }
  }
  float rinv[2][4];
#pragma unroll
  for (int qc = 0; qc < 2; ++qc)
#pragma unroll
    for (int r = 0; r < 4; ++r) {
      float s = sum[qc][r];
#pragma unroll
      for (int sh = 1; sh < 16; sh <<= 1)
        s += __shfl_xor(s, sh, 64);
      rinv[qc][r] = 1.0f / s;
    }

  // ---- pass 2 ----
  f32x4 oacc[2][8];
#pragma unroll
  for (int qc = 0; qc < 2; ++qc)
#pragma unroll
    for (int i = 0; i < 8; ++i) oacc[qc][i] = (f32x4){0.f, 0.f, 0.f, 0.f};

  BARRIER();
  stageK(0, 0);
  for (int gp = 0; gp < ntB; ++gp) {
    BARRIER();
    stageV(gp);
    const bool hn = (gp + 1 < ntB);
    if (hn) stageK(gp + 1, (gp + 1) & 1);
    if (gp == 0) { WAITN(8); }
    else if (hn) { WAITN(40); }
    else         { WAITN(36); }
    BARRIER();
    const bool act = gp < ntW;
    float pv[2][4][4];
    if (act) {
      f32x4 acc[2][4];
#pragma unroll
      for (int qc = 0; qc < 2; ++qc)
#pragma unroll
        for (int t = 0; t < 4; ++t) acc[qc][t] = (f32x4){0.f,0.f,0.f,0.f};
      qkt(&Klds[gp & 1][0], acc);
      if (gp < ntW - 1) {
#pragma unroll
        for (int qc = 0; qc < 2; ++qc)
#pragma unroll
          for (int t = 0; t < 4; ++t)
#pragma unroll
            for (int r = 0; r < 4; ++r)
              pv[qc][t][r] = exp2f(acc[qc][t][r] * sc2) * rinv[qc][r];
      } else {
#pragma unroll
        for (int qc = 0; qc < 2; ++qc)
#pragma unroll
          for (int t = 0; t < 4; ++t)
#pragma unroll
            for (int r = 0; r < 4; ++r) {
              int kc = gp * 64 + t * 16 + l15;
              int qr = q0w + qc * 16 + lg * 4 + r;
              pv[qc][t][r] = (kc <= qr) ? exp2f(acc[qc][t][r] * sc2) * rinv[qc][r] : 0.f;
            }
      }
#pragma unroll
      for (int qc = 0; qc < 2; ++qc)
#pragma unroll
        for (int t = 0; t < 4; ++t)
#pragma unroll
          for (int r = 0; r < 4; ++r)
            Plds[w][qc * 16 + lg * 4 + r][t * 16 + l15] = (bf16)pv[qc][t][r];
    }
    if (hn) WAITN(4); else WAITN(0);
    if (act) {
#pragma unroll
      for (int qc = 0; qc < 2; ++qc)
#pragma unroll
        for (int t = 0; t < 4; ++t)
#pragma unroll
          for (int r = 0; r < 4; ++r)
            arow[(size_t)(qc * 16 + lg * 4 + r) * L_ + gp * 64 + t * 16 + l15] = pv[qc][t][r];
    } else {
      zstore32(gp);
    }
    BARRIER();
    if (act) {
      asm volatile("s_waitcnt lgkmcnt(0)" ::: "memory");
      __builtin_amdgcn_sched_barrier(0);
      bf16x8 pa[2][2];
#pragma unroll
      for (int qc = 0; qc < 2; ++qc)
#pragma unroll
        for (int ck = 0; ck < 2; ++ck)
          pa[qc][ck] = *reinterpret_cast<const bf16x8*>(&Plds[w][qc * 16 + l15][ck * 32 + lg * 8]);
#pragma unroll
      for (int ck = 0; ck < 2; ++ck)
#pragma unroll
        for (int t8 = 0; t8 < 8; ++t8) {
          bf16x8 vf = *reinterpret_cast<const bf16x8*>(
              Vlds + (t8 * 16 + l15) * 64 + ((((ck << 2) + lg) ^ (l15 & 7)) << 3));
#pragma unroll
          for (int qc = 0; qc < 2; ++qc)
            oacc[qc][t8] = __builtin_amdgcn_mfma_f32_16x16x32_bf16(pa[qc][ck], vf, oacc[qc][t8], 0, 0, 0);
        }
      asm volatile("s_waitcnt lgkmcnt(0)" ::: "memory");
    }
  }

  for (int gp2 = ntB; gp2 < 32; ++gp2) {
#pragma unroll
    for (int i = 0; i < 8; ++i)
      *reinterpret_cast<f32x4*>(arow + (size_t)(i * 4 + lg) * L_ + gp2 * 64 + l15 * 4)
          = (f32x4){0.f, 0.f, 0.f, 0.f};
  }

#pragma unroll
  for (int qc = 0; qc < 2; ++qc) {
    bf16* orow = Oh + ((size_t)b * L_ + q0w + qc * 16) * D_ + h * HD_;
#pragma unroll
    for (int t8 = 0; t8 < 8; ++t8)
#pragma unroll
      for (int r = 0; r < 4; ++r)
        orow[(size_t)(lg * 4 + r) * D_ + t8 * 16 + l15] = (bf16)oacc[qc][t8][r];
  }
}

// ---------------- host ----------------
extern "C" void kernel_launch(void* const* d_in, const int* in_sizes, int n_in,
                              void* d_out, int out_size, void* d_ws, size_t ws_size,
                              hipStream_t stream) {
  const float* x_q  = (const float*)d_in[0];
  const float* x_kv = (const float*)d_in[1];
  const float* w_q = (const float*)d_in[3];
  const float* w_k = (const float*)d_in[4];
  const float* w_v = (const float*)d_in[5];
  const float* w_o = (const float*)d_in[6];

  char* p = (char*)d_ws;
  auto alloc = [&](size_t bytes) { char* r = p; p += (bytes + 255) & ~(size_t)255; return r; };
  bf16* xq_b  = (bf16*)alloc((size_t)E_ * 2);
  bf16* xkv_b = (bf16*)alloc((size_t)E_ * 2);
  bf16* wq_b  = (bf16*)alloc((size_t)W_ * 2);
  bf16* wk_b  = (bf16*)alloc((size_t)W_ * 2);
  bf16* wv_b  = (bf16*)alloc((size_t)W_ * 2);
  bf16* wo_b  = (bf16*)alloc((size_t)W_ * 2);
  bf16* Qraw  = (bf16*)alloc((size_t)E_ * 2);
  bf16* Kraw  = (bf16*)alloc((size_t)E_ * 2);
  bf16* Vt    = (bf16*)alloc((size_t)E_ * 2);
  bf16* Oh    = (bf16*)alloc((size_t)E_ * 2);
  float* ct   = (float*)alloc((size_t)L_ * 64 * 4);
  float* st2  = (float*)alloc((size_t)L_ * 64 * 4);

  float* out0     = (float*)d_out;
  float* attn_out = out0 + E_;

  prep<<<33280, 256, 0, stream>>>(x_q, x_kv, w_q, w_k, w_v, w_o,
                                  xq_b, xkv_b, wq_b, wk_b, wv_b, wo_b, ct, st2);
  gemm_qkv8p<<<dim3(24, 32), 512, 0, stream>>>(xq_b, xkv_b, wq_b, wk_b, wv_b,
                                               ct, st2, Qraw, Kraw, Vt);
  attn_fused<<<dim3(16, 32), 256, 0, stream>>>(Qraw, Kraw, Vt, attn_out, Oh);
  gemm_bt<<<dim3(16, 32), 256, 0, stream>>>(Oh, wo_b, out0, B_*L_, D_, D_);
}

// Round 11
// 391.452 us; speedup vs baseline: 1.1657x; 1.0457x over previous
//
#include <hip/hip_runtime.h>
#include <hip/hip_bf16.h>
#include <math.h>

#define B_ 2
#define L_ 2048
#define D_ 2048
#define H_ 16
#define HD_ 128
#define E_ (B_*L_*D_)   // 8388608
#define W_ (D_*D_)      // 4194304

typedef __bf16 bf16;
typedef __bf16 bf16x8 __attribute__((ext_vector_type(8)));
typedef __bf16 bf16x4 __attribute__((ext_vector_type(4)));
typedef float  f32x4  __attribute__((ext_vector_type(4)));

// async global->LDS, 16B per lane; lds ptr must be wave-uniform
#define GLL16(gp_, lp_) __builtin_amdgcn_global_load_lds( \
    (const __attribute__((address_space(1))) void*)(gp_), \
    (__attribute__((address_space(3))) void*)(lp_), 16, 0, 0)

#define BARRIER() do { asm volatile("" ::: "memory"); \
    __builtin_amdgcn_s_barrier(); \
    asm volatile("" ::: "memory"); } while (0)

#define WAITN(N) asm volatile("s_waitcnt vmcnt(" #N ")" ::: "memory")

// ---------------- prep: all f32->bf16 converts + rope table, one launch ----------------
__global__ void prep(const float* __restrict__ xq, const float* __restrict__ xkv,
                     const float* __restrict__ wq, const float* __restrict__ wk,
                     const float* __restrict__ wv, const float* __restrict__ wo,
                     bf16* __restrict__ xqb, bf16* __restrict__ xkvb,
                     bf16* __restrict__ wqb, bf16* __restrict__ wkb,
                     bf16* __restrict__ wvb, bf16* __restrict__ wob,
                     float* __restrict__ ct, float* __restrict__ st) {
  int g = blockIdx.x;
  if (g < 16384) {
    const float* s = (g < 8192) ? xq : xkv;
    bf16* d = (g < 8192) ? xqb : xkvb;
    int i = ((g & 8191) * 256 + threadIdx.x) * 4;
    f32x4 v = *reinterpret_cast<const f32x4*>(s + i);
    bf16x4 o; o[0]=(bf16)v[0]; o[1]=(bf16)v[1]; o[2]=(bf16)v[2]; o[3]=(bf16)v[3];
    *reinterpret_cast<bf16x4*>(d + i) = o;
  } else if (g < 32768) {
    int gg = g - 16384;
    int which = gg >> 12;
    const float* s = (which==0)?wq:(which==1)?wk:(which==2)?wv:wo;
    bf16* d = (which==0)?wqb:(which==1)?wkb:(which==2)?wvb:wob;
    int i = ((gg & 4095) * 256 + threadIdx.x) * 4;
    f32x4 v = *reinterpret_cast<const f32x4*>(s + i);
    bf16x4 o; o[0]=(bf16)v[0]; o[1]=(bf16)v[1]; o[2]=(bf16)v[2]; o[3]=(bf16)v[3];
    *reinterpret_cast<bf16x4*>(d + i) = o;
  } else {
    int idx = (g - 32768) * 256 + threadIdx.x;   // < 131072 = 2048*64
    int t = idx >> 6, i = idx & 63;
    float inv = powf(10000.0f, -2.0f * (float)i / 128.0f);
    float f = (float)t * inv;
    ct[t * 64 + i] = cosf(f);
    st[t * 64 + i] = sinf(f);
  }
}

// ---------------- fused QKV GEMM + RoPE epilogue + V-transpose epilogue (round-6) ----------------
__global__ __launch_bounds__(256, 4) void gemm_qkv(
    const bf16* __restrict__ xq, const bf16* __restrict__ xkv,
    const bf16* __restrict__ wq, const bf16* __restrict__ wk, const bf16* __restrict__ wv,
    const float* __restrict__ ct, const float* __restrict__ st,
    bf16* __restrict__ Qo, bf16* __restrict__ Ko, bf16* __restrict__ Vt) {
  __shared__ bf16 As[128 * 64];
  __shared__ bf16 Bs[128 * 64];
  const int tid = threadIdx.x;
  const int lane = tid & 63;
  const int w = tid >> 6;
  const int l15 = lane & 15, lg = lane >> 4;
  const int which = blockIdx.x >> 4;            // 0=Q, 1=K, 2=V
  const int n0 = (blockIdx.x & 15) * 128;
  const int m0 = blockIdx.y * 128;
  const int wm = (w >> 1) * 64, wn = (w & 1) * 64;
  const bf16* A  = (which == 0) ? xq : xkv;
  const bf16* Wt = (which == 0) ? wq : ((which == 1) ? wk : wv);

  int rowS[4], schS[4];
#pragma unroll
  for (int s = 0; s < 4; ++s) {
    int cl = s * 256 + tid;
    rowS[s] = cl >> 3;
    schS[s] = ((cl & 7) ^ ((cl >> 3) & 7)) << 3;
  }

  f32x4 acc[4][4];
#pragma unroll
  for (int m = 0; m < 4; ++m)
#pragma unroll
    for (int n = 0; n < 4; ++n) acc[m][n] = (f32x4){0.f, 0.f, 0.f, 0.f};

  for (int kt = 0; kt < D_; kt += 64) {
    __syncthreads();
#pragma unroll
    for (int s = 0; s < 4; ++s) {
      GLL16(A  + (size_t)(m0 + rowS[s]) * D_ + kt + schS[s], As + s * 2048 + w * 512);
      GLL16(Wt + (size_t)(n0 + rowS[s]) * D_ + kt + schS[s], Bs + s * 2048 + w * 512);
    }
    __syncthreads();
#pragma unroll
    for (int kk = 0; kk < 64; kk += 32) {
      bf16x8 af[4], bfr[4];
#pragma unroll
      for (int m = 0; m < 4; ++m)
        af[m] = *reinterpret_cast<const bf16x8*>(
            As + (wm + m * 16 + l15) * 64 + ((((kk >> 3) + lg) ^ (l15 & 7)) << 3));
#pragma unroll
      for (int n = 0; n < 4; ++n)
        bfr[n] = *reinterpret_cast<const bf16x8*>(
            Bs + (wn + n * 16 + l15) * 64 + ((((kk >> 3) + lg) ^ (l15 & 7)) << 3));
#pragma unroll
      for (int m = 0; m < 4; ++m)
#pragma unroll
        for (int n = 0; n < 4; ++n)
          acc[m][n] = __builtin_amdgcn_mfma_f32_16x16x32_bf16(af[m], bfr[n], acc[m][n], 0, 0, 0);
    }
  }

  if (which == 2) {
    const int b = m0 >> 11;
    const int l0b = (m0 & 2047) + wm + lg * 4;
#pragma unroll
    for (int m = 0; m < 4; ++m) {
      int l0 = l0b + m * 16;
#pragma unroll
      for (int n = 0; n < 4; ++n) {
        int c = n0 + wn + n * 16 + l15;
        int hd = (b * 16 + (c >> 7)) * 128 + (c & 127);
        bf16x4 o;
        o[0] = (bf16)acc[m][n][0]; o[1] = (bf16)acc[m][n][1];
        o[2] = (bf16)acc[m][n][2]; o[3] = (bf16)acc[m][n][3];
        *reinterpret_cast<bf16x4*>(Vt + (size_t)hd * L_ + l0) = o;
      }
    }
  } else {
    bf16* Out = which ? Ko : Qo;
    const bool odd = (l15 & 1);
#pragma unroll
    for (int m = 0; m < 4; ++m) {
      int row = m0 + wm + m * 16 + lg * 4;
      int l = row & 2047;
#pragma unroll
      for (int n = 0; n < 4; ++n) {
        int c = n0 + wn + n * 16 + l15;
        int i = (c & 127) >> 1;
#pragma unroll
        for (int r = 0; r < 4; ++r) {
          float own = acc[m][n][r];
          float prt = __shfl_xor(own, 1, 64);
          float cc = ct[(size_t)(l + r) * 64 + i];
          float ss = st[(size_t)(l + r) * 64 + i];
          float res = odd ? (prt * ss + own * cc) : (own * cc - prt * ss);
          Out[(size_t)(row + r) * D_ + c] = (bf16)res;
        }
      }
    }
  }
}

// ---------------- GEMM: C[M,N] = A[M,K] @ Bw[N,K]^T (m97 structure, f32 out) ----------------
__global__ __launch_bounds__(256, 4) void gemm_bt(const bf16* __restrict__ A,
                                                  const bf16* __restrict__ Bw,
                                                  float* __restrict__ Cout,
                                                  int M, int N, int K) {
  __shared__ bf16 As[128 * 64];
  __shared__ bf16 Bs[128 * 64];
  const int tid = threadIdx.x;
  const int lane = tid & 63;
  const int w = tid >> 6;
  const int l15 = lane & 15, lg = lane >> 4;
  const int m0 = blockIdx.y * 128, n0 = blockIdx.x * 128;
  const int wm = (w >> 1) * 64, wn = (w & 1) * 64;

  int rowS[4], schS[4];
#pragma unroll
  for (int s = 0; s < 4; ++s) {
    int cl = s * 256 + tid;
    rowS[s] = cl >> 3;
    schS[s] = ((cl & 7) ^ ((cl >> 3) & 7)) << 3;
  }

  f32x4 acc[4][4];
#pragma unroll
  for (int m = 0; m < 4; ++m)
#pragma unroll
    for (int n = 0; n < 4; ++n) acc[m][n] = (f32x4){0.f, 0.f, 0.f, 0.f};

  for (int kt = 0; kt < K; kt += 64) {
    __syncthreads();
#pragma unroll
    for (int s = 0; s < 4; ++s) {
      GLL16(A  + (size_t)(m0 + rowS[s]) * K + kt + schS[s], As + s * 2048 + w * 512);
      GLL16(Bw + (size_t)(n0 + rowS[s]) * K + kt + schS[s], Bs + s * 2048 + w * 512);
    }
    __syncthreads();
#pragma unroll
    for (int kk = 0; kk < 64; kk += 32) {
      bf16x8 af[4], bfr[4];
#pragma unroll
      for (int m = 0; m < 4; ++m)
        af[m] = *reinterpret_cast<const bf16x8*>(
            As + (wm + m * 16 + l15) * 64 + ((((kk >> 3) + lg) ^ (l15 & 7)) << 3));
#pragma unroll
      for (int n = 0; n < 4; ++n)
        bfr[n] = *reinterpret_cast<const bf16x8*>(
            Bs + (wn + n * 16 + l15) * 64 + ((((kk >> 3) + lg) ^ (l15 & 7)) << 3));
#pragma unroll
      for (int m = 0; m < 4; ++m)
#pragma unroll
        for (int n = 0; n < 4; ++n)
          acc[m][n] = __builtin_amdgcn_mfma_f32_16x16x32_bf16(af[m], bfr[n], acc[m][n], 0, 0, 0);
    }
  }
#pragma unroll
  for (int m = 0; m < 4; ++m) {
    int orow = m0 + wm + m * 16 + lg * 4;
#pragma unroll
    for (int n = 0; n < 4; ++n) {
      int col = n0 + wn + n * 16 + l15;
#pragma unroll
      for (int r = 0; r < 4; ++r)
        Cout[(size_t)(orow + r) * N + col] = acc[m][n][r];
    }
  }
}

// ---------------- fused causal attention: pass-1 paired groups, pass-2 = round 6 ----------------
__global__ __launch_bounds__(256, 2) void attn_fused(const bf16* __restrict__ Qb,
                                                     const bf16* __restrict__ Kb,
                                                     const bf16* __restrict__ Vt,
                                                     float* __restrict__ attn,
                                                     bf16* __restrict__ Oh) {
  __shared__ bf16 Klds[2][64 * 128];   // 32 KB
  __shared__ bf16 Vlds[128 * 64];      // 16 KB (pass-1: K buffer #2)
  __shared__ bf16 Plds[4][32][72];     // 18 KB (pass-1: K buffer #3)

  const int tid = threadIdx.x;
  const int w = tid >> 6, lane = tid & 63;
  const int l15 = lane & 15, lg = lane >> 4;

  int g = blockIdx.x + 16 * blockIdx.y;
  int tq, bh;
  if (g < 256) { tq = g & 15;  bh = g >> 4; }
  else { int h2 = g - 256; tq = 15 - (h2 & 15); bh = 16 + (h2 >> 4); }
  const int b = bh >> 4, h = bh & 15;

  const int q0w = tq * 128 + w * 32;
  const int ntW = (q0w >> 6) + 1;
  const int ntB = 2 * tq + 2;               // even
  const float sc2 = 0.08838834764831845f * 1.44269504088896f;

  const bf16* kb = Kb + ((size_t)b * L_) * D_ + h * HD_;
  const bf16* vb = Vt + (size_t)bh * HD_ * L_;
  float* arow = attn + ((size_t)bh * L_ + q0w) * L_;

  // runtime LDS buffer select (pointer-array initializer is rejected by hipcc)
  auto kbufp = [&](int i) -> bf16* {
    switch (i) {
      case 0:  return &Klds[0][0];
      case 1:  return &Klds[1][0];
      case 2:  return Vlds;
      default: return (bf16*)&Plds[0][0][0];
    }
  };

  bf16x8 qf[2][4];
#pragma unroll
  for (int qc = 0; qc < 2; ++qc) {
    const bf16* qrow = Qb + ((size_t)b * L_ + q0w + qc * 16 + l15) * D_ + h * HD_;
#pragma unroll
    for (int c = 0; c < 4; ++c)
      qf[qc][c] = *reinterpret_cast<const bf16x8*>(qrow + c * 32 + lg * 8);
  }

  int rK[4], sK[4], rV[4], sV[4];
#pragma unroll
  for (int s = 0; s < 4; ++s) {
    int ck = s * 256 + tid;
    rK[s] = ck >> 4; sK[s] = ((ck & 15) ^ (rK[s] & 7)) << 3;
    rV[s] = ck >> 3; sV[s] = ((ck & 7) ^ (rV[s] & 7)) << 3;
  }

  auto stageKto = [&](int gp, bf16* dst) {
#pragma unroll
    for (int s = 0; s < 4; ++s)
      GLL16(kb + (size_t)(gp * 64 + rK[s]) * D_ + sK[s], dst + s * 2048 + w * 512);
  };
  auto stageV = [&](int gp) {
#pragma unroll
    for (int s = 0; s < 4; ++s)
      GLL16(vb + (size_t)rV[s] * L_ + gp * 64 + sV[s],
            Vlds + s * 2048 + w * 512);
  };
  auto qkt = [&](const bf16* kl, f32x4 acc[2][4]) {
#pragma unroll
    for (int c = 0; c < 4; ++c)
#pragma unroll
      for (int t = 0; t < 4; ++t) {
        bf16x8 kf = *reinterpret_cast<const bf16x8*>(
            kl + (t * 16 + l15) * 128 + ((((c << 2) + lg) ^ (l15 & 7)) << 3));
#pragma unroll
        for (int qc = 0; qc < 2; ++qc)
          acc[qc][t] = __builtin_amdgcn_mfma_f32_16x16x32_bf16(qf[qc][c], kf, acc[qc][t], 0, 0, 0);
      }
  };
  auto zstore32 = [&](int gp) {
#pragma unroll
    for (int qc = 0; qc < 2; ++qc)
#pragma unroll
      for (int t = 0; t < 4; ++t)
#pragma unroll
        for (int r = 0; r < 4; ++r)
          arow[(size_t)(qc * 16 + lg * 4 + r) * L_ + gp * 64 + t * 16 + l15] = 0.f;
  };

  // ---- pass 1: row sums; 2 groups per barrier pair, 4 K buffers, no stores ----
  float sum[2][4] = {{0.f,0.f,0.f,0.f},{0.f,0.f,0.f,0.f}};
  const int npair = ntB >> 1;               // = tq+1
  stageKto(0, kbufp(0));
  stageKto(1, kbufp(1));
  for (int p = 0; p < npair; ++p) {
    BARRIER();                              // A: reads of the pair being overwritten are done
    const bool hn = (p + 1 < npair);
    if (hn) {
      stageKto(2 * p + 2, kbufp(2 * ((p + 1) & 1)));
      stageKto(2 * p + 3, kbufp(2 * ((p + 1) & 1) + 1));
      WAITN(8);                             // pair p landed; pair p+1 in flight
    } else {
      WAITN(0);
    }
    BARRIER();                              // B: pair p visible to all
#pragma unroll
    for (int half = 0; half < 2; ++half) {
      int gp = 2 * p + half;
      if (gp < ntW) {
        f32x4 acc[2][4];
#pragma unroll
        for (int qc = 0; qc < 2; ++qc)
#pragma unroll
          for (int t = 0; t < 4; ++t) acc[qc][t] = (f32x4){0.f,0.f,0.f,0.f};
        qkt(kbufp(2 * (p & 1) + half), acc);
        if (gp < ntW - 1) {
#pragma unroll
          for (int qc = 0; qc < 2; ++qc)
#pragma unroll
            for (int t = 0; t < 4; ++t)
#pragma unroll
              for (int r = 0; r < 4; ++r)
                sum[qc][r] += exp2f(acc[qc][t][r] * sc2);
        } else {
#pragma unroll
          for (int qc = 0; qc < 2; ++qc)
#pragma unroll
            for (int t = 0; t < 4; ++t)
#pragma unroll
              for (int r = 0; r < 4; ++r) {
                int kc = gp * 64 + t * 16 + l15;
                int qr = q0w + qc * 16 + lg * 4 + r;
                sum[qc][r] += (kc <= qr) ? exp2f(acc[qc][t][r] * sc2) : 0.f;
              }
        }
      }
    }
  }
  float rinv[2][4];
#pragma unroll
  for (int qc = 0; qc < 2; ++qc)
#pragma unroll
    for (int r = 0; r < 4; ++r) {
      float s = sum[qc][r];
#pragma unroll
      for (int sh = 1; sh < 16; sh <<= 1)
        s += __shfl_xor(s, sh, 64);
      rinv[qc][r] = 1.0f / s;
    }

  // ---- pass 2: identical to round 6 ----
  f32x4 oacc[2][8];
#pragma unroll
  for (int qc = 0; qc < 2; ++qc)
#pragma unroll
    for (int i = 0; i < 8; ++i) oacc[qc][i] = (f32x4){0.f, 0.f, 0.f, 0.f};

  BARRIER();
  stageKto(0, &Klds[0][0]);
  for (int gp = 0; gp < ntB; ++gp) {
    BARRIER();
    stageV(gp);
    const bool hn = (gp + 1 < ntB);
    if (hn) stageKto(gp + 1, &Klds[(gp + 1) & 1][0]);
    if (gp == 0) { WAITN(8); }
    else if (hn) { WAITN(40); }
    else         { WAITN(36); }
    BARRIER();
    const bool act = gp < ntW;
    float pv[2][4][4];
    if (act) {
      f32x4 acc[2][4];
#pragma unroll
      for (int qc = 0; qc < 2; ++qc)
#pragma unroll
        for (int t = 0; t < 4; ++t) acc[qc][t] = (f32x4){0.f,0.f,0.f,0.f};
      qkt(&Klds[gp & 1][0], acc);
      if (gp < ntW - 1) {
#pragma unroll
        for (int qc = 0; qc < 2; ++qc)
#pragma unroll
          for (int t = 0; t < 4; ++t)
#pragma unroll
            for (int r = 0; r < 4; ++r)
              pv[qc][t][r] = exp2f(acc[qc][t][r] * sc2) * rinv[qc][r];
      } else {
#pragma unroll
        for (int qc = 0; qc < 2; ++qc)
#pragma unroll
          for (int t = 0; t < 4; ++t)
#pragma unroll
            for (int r = 0; r < 4; ++r) {
              int kc = gp * 64 + t * 16 + l15;
              int qr = q0w + qc * 16 + lg * 4 + r;
              pv[qc][t][r] = (kc <= qr) ? exp2f(acc[qc][t][r] * sc2) * rinv[qc][r] : 0.f;
            }
      }
#pragma unroll
      for (int qc = 0; qc < 2; ++qc)
#pragma unroll
        for (int t = 0; t < 4; ++t)
#pragma unroll
          for (int r = 0; r < 4; ++r)
            Plds[w][qc * 16 + lg * 4 + r][t * 16 + l15] = (bf16)pv[qc][t][r];
    }
    if (hn) WAITN(4); else WAITN(0);
    if (act) {
#pragma unroll
      for (int qc = 0; qc < 2; ++qc)
#pragma unroll
        for (int t = 0; t < 4; ++t)
#pragma unroll
          for (int r = 0; r < 4; ++r)
            arow[(size_t)(qc * 16 + lg * 4 + r) * L_ + gp * 64 + t * 16 + l15] = pv[qc][t][r];
    } else {
      zstore32(gp);
    }
    BARRIER();
    if (act) {
      asm volatile("s_waitcnt lgkmcnt(0)" ::: "memory");
      __builtin_amdgcn_sched_barrier(0);
      bf16x8 pa[2][2];
#pragma unroll
      for (int qc = 0; qc < 2; ++qc)
#pragma unroll
        for (int ck = 0; ck < 2; ++ck)
          pa[qc][ck] = *reinterpret_cast<const bf16x8*>(&Plds[w][qc * 16 + l15][ck * 32 + lg * 8]);
#pragma unroll
      for (int ck = 0; ck < 2; ++ck)
#pragma unroll
        for (int t8 = 0; t8 < 8; ++t8) {
          bf16x8 vf = *reinterpret_cast<const bf16x8*>(
              Vlds + (t8 * 16 + l15) * 64 + ((((ck << 2) + lg) ^ (l15 & 7)) << 3));
#pragma unroll
          for (int qc = 0; qc < 2; ++qc)
            oacc[qc][t8] = __builtin_amdgcn_mfma_f32_16x16x32_bf16(pa[qc][ck], vf, oacc[qc][t8], 0, 0, 0);
        }
      asm volatile("s_waitcnt lgkmcnt(0)" ::: "memory");
    }
  }

  for (int gp2 = ntB; gp2 < 32; ++gp2) {
#pragma unroll
    for (int i = 0; i < 8; ++i)
      *reinterpret_cast<f32x4*>(arow + (size_t)(i * 4 + lg) * L_ + gp2 * 64 + l15 * 4)
          = (f32x4){0.f, 0.f, 0.f, 0.f};
  }

#pragma unroll
  for (int qc = 0; qc < 2; ++qc) {
    bf16* orow = Oh + ((size_t)b * L_ + q0w + qc * 16) * D_ + h * HD_;
#pragma unroll
    for (int t8 = 0; t8 < 8; ++t8)
#pragma unroll
      for (int r = 0; r < 4; ++r)
        orow[(size_t)(lg * 4 + r) * D_ + t8 * 16 + l15] = (bf16)oacc[qc][t8][r];
  }
}

// ---------------- host ----------------
extern "C" void kernel_launch(void* const* d_in, const int* in_sizes, int n_in,
                              void* d_out, int out_size, void* d_ws, size_t ws_size,
                              hipStream_t stream) {
  const float* x_q  = (const float*)d_in[0];
  const float* x_kv = (const float*)d_in[1];
  const float* w_q = (const float*)d_in[3];
  const float* w_k = (const float*)d_in[4];
  const float* w_v = (const float*)d_in[5];
  const float* w_o = (const float*)d_in[6];

  char* p = (char*)d_ws;
  auto alloc = [&](size_t bytes) { char* r = p; p += (bytes + 255) & ~(size_t)255; return r; };
  bf16* xq_b  = (bf16*)alloc((size_t)E_ * 2);
  bf16* xkv_b = (bf16*)alloc((size_t)E_ * 2);
  bf16* wq_b  = (bf16*)alloc((size_t)W_ * 2);
  bf16* wk_b  = (bf16*)alloc((size_t)W_ * 2);
  bf16* wv_b  = (bf16*)alloc((size_t)W_ * 2);
  bf16* wo_b  = (bf16*)alloc((size_t)W_ * 2);
  bf16* Qraw  = (bf16*)alloc((size_t)E_ * 2);
  bf16* Kraw  = (bf16*)alloc((size_t)E_ * 2);
  bf16* Vt    = (bf16*)alloc((size_t)E_ * 2);
  bf16* Oh    = (bf16*)alloc((size_t)E_ * 2);
  float* ct   = (float*)alloc((size_t)L_ * 64 * 4);
  float* st2  = (float*)alloc((size_t)L_ * 64 * 4);

  float* out0     = (float*)d_out;
  float* attn_out = out0 + E_;

  prep<<<33280, 256, 0, stream>>>(x_q, x_kv, w_q, w_k, w_v, w_o,
                                  xq_b, xkv_b, wq_b, wk_b, wv_b, wo_b, ct, st2);
  gemm_qkv<<<dim3(48, 32), 256, 0, stream>>>(xq_b, xkv_b, wq_b, wk_b, wv_b,
                                             ct, st2, Qraw, Kraw, Vt);
  attn_fused<<<dim3(16, 32), 256, 0, stream>>>(Qraw, Kraw, Vt, attn_out, Oh);
  gemm_bt<<<dim3(16, 32), 256, 0, stream>>>(Oh, wo_b, out0, B_*L_, D_, D_);
}